// Round 6
// baseline (11548.406 us; speedup 1.0000x reference)
//
#include <hip/hip_runtime.h>

// ---------------------------------------------------------------------------
// TTS forward on MI355X.
//   embed -> conv1(+BN+ReLU) -> conv2(+BN+ReLU) -> persistent biLSTM encoder
//   -> W_eff fold (decoder input GEMM folded into recurrent weights)
//   -> persistent 800-step decoder LSTM + lagging projection consumer blocks
// Round 9: fewer exchange parties. Decoder: 32 core blocks x 1024 thr (each
// owns 32 h-elems; 16 waves, 1 tile/wave as before) + 2 projection blocks.
// Encoder: 32 blocks x 1024 thr (16 per direction). Same round-7 exchange
// machinery (atomic-swap data, vmcnt ack on the single storing wave, flag
// fan-out to private mailboxes, poll-one-wave -> barrier -> contiguous
// cooperative load). Halves fan-out, flag lines, LLC load burst, straggler
// pool. Full 64KB encoder slot 0 now zeroed (was only half).
// ---------------------------------------------------------------------------

typedef float f4 __attribute__((ext_vector_type(4)));
typedef _Float16 h8 __attribute__((ext_vector_type(8)));
typedef _Float16 half_t;
typedef unsigned long long u64;

#define B_    32
#define LTXT  256
#define TMEL  800
#define EE    512
#define HH    512
#define DD    1024
#define MM    128
#define NROWS 8192          // B_*LTXT
#define GATE_OFF 3276800    // B_*TMEL*MM
#define MASK_OFF 3302400    // + B_*TMEL

#define RING_D 801          // decoder h ring slots (never reused in 800 steps)
#define RING_E 257          // encoder h ring slots
#define HOP    13           // slot hop stride (coprime with both rings)

// workspace offsets (bytes)
#define WS_MBE        0ull             // enc mailboxes: 32 consumers x 64 u32 (16 KiB rsvd)
#define WS_MBD        16384ull         // dec mailboxes: 34 consumers x 64 u32 (16 KiB rsvd)
#define WS_HENC       32768ull         // RING_E * 65536
#define WS_ZERO_BYTES 98304ull         // mailboxes + FULL henc slot 0
#define WS_HD         16875520ull      // RING_D * 65536
#define WS_BUFX       69369856ull      // 8 MiB
#define WS_BUFY       77758464ull      // 8 MiB
#define WS_CONVF      86147072ull      // 16 MiB (reused by WEFF/W0 after convs)
#define WS_WEFF       86147072ull
#define WS_W0         94535680ull
#define WS_WP1        102924288ull
#define WS_WP2        104497152ull
#define WS_WIHP       106070016ull     // 4 MiB
#define WS_WHHP       110264320ull     // 4 MiB
#define WS_BSUM       114458624ull
#define WS_BEFF       114475008ull
#define WS_B0         114491392ull
#define WS_MEAN       114507776ull
#define WS_RSTD       114509824ull
#define WS_PROJW      114511872ull
#define WS_PROJG      114774016ull
#define WS_CEL        114806784ull
// total ~114.9 MB

__device__ __forceinline__ float sigm(float x) { return 1.f / (1.f + __expf(-x)); }
__device__ __forceinline__ float tanh_f(float x) {
    float e = __expf(2.f * x);
    return 1.f - 2.f / (e + 1.f);
}

// return-less atomic swap: executes at coherence point, line stays L3-resident
__device__ __forceinline__ void st_atom64(void* p, u64 v) {
    asm volatile("global_atomic_swap_x2 %0, %1, off" :: "v"(p), "v"(v) : "memory");
}
__device__ __forceinline__ void st_atom32(unsigned* p, unsigned v) {
    asm volatile("global_atomic_swap %0, %1, off" :: "v"(p), "v"(v) : "memory");
}

// ---------------- small prep kernels ----------------

__global__ void k_embed(const int* __restrict__ x, const float* __restrict__ emb,
                        half_t* __restrict__ out) {
    int row = blockIdx.x;
    int tok = x[row];
    const float* e = emb + (size_t)tok * EE;
    half_t* o = out + (size_t)row * EE;
    for (int c = threadIdx.x; c < EE; c += blockDim.x) o[c] = (half_t)e[c];
}

__global__ void k_packconvw(const float* __restrict__ w, half_t* __restrict__ wp) {
    int idx = blockIdx.x * 256 + threadIdx.x;
    if (idx >= 3 * EE * EE) return;
    int s = idx / (EE * EE);
    int rem = idx - s * EE * EE;
    int eo = rem >> 9, ei = rem & 511;
    wp[idx] = (half_t)w[(size_t)eo * (EE * 3) + ei * 3 + s];
}

__global__ __launch_bounds__(256) void k_conv(const half_t* __restrict__ A,
                                              const half_t* __restrict__ Wp,
                                              const float* __restrict__ bias,
                                              float* __restrict__ out) {
    const int nt = blockIdx.x, et = blockIdx.y;
    const int tid = threadIdx.x;
    const int wv = tid >> 6, l = tid & 63, quad = l >> 4, lo = l & 15;
    const int rowA = nt * 64 + wv * 16 + lo;
    const int eo = et * 16 + lo;
    f4 acc = {0.f, 0.f, 0.f, 0.f};
    for (int s = 0; s < 3; ++s) {
        int lsp = (rowA & 255) + s - 1;
        bool valid = (lsp >= 0) && (lsp < 256);
        int rs = rowA + s - 1;
        rs = rs < 0 ? 0 : (rs > NROWS - 1 ? NROWS - 1 : rs);
        const half_t* ab = A + (size_t)rs * EE;
        const half_t* wb = Wp + ((size_t)s * EE + eo) * EE;
#pragma unroll 4
        for (int ks = 0; ks < 16; ++ks) {
            h8 a = {0, 0, 0, 0, 0, 0, 0, 0};
            if (valid) a = *(const h8*)(ab + ks * 32 + quad * 8);
            h8 b = *(const h8*)(wb + ks * 32 + quad * 8);
            acc = __builtin_amdgcn_mfma_f32_16x16x32_f16(a, b, acc, 0, 0, 0);
        }
    }
    const int orow = nt * 64 + wv * 16 + quad * 4;
    const float bv = bias[eo];
#pragma unroll
    for (int r = 0; r < 4; ++r) out[(size_t)(orow + r) * EE + eo] = acc[r] + bv;
}

__global__ __launch_bounds__(256) void k_bnstats(const float* __restrict__ x,
                                                 float* __restrict__ mean,
                                                 float* __restrict__ rstd) {
    const int c = blockIdx.x;
    float s = 0.f, ss = 0.f;
    for (int n = threadIdx.x; n < NROWS; n += 256) {
        float v = x[(size_t)n * EE + c];
        s += v; ss += v * v;
    }
#pragma unroll
    for (int off = 32; off > 0; off >>= 1) { s += __shfl_down(s, off); ss += __shfl_down(ss, off); }
    __shared__ float as[4], ass[4];
    int wv = threadIdx.x >> 6;
    if ((threadIdx.x & 63) == 0) { as[wv] = s; ass[wv] = ss; }
    __syncthreads();
    if (threadIdx.x == 0) {
        float S = as[0] + as[1] + as[2] + as[3];
        float SS = ass[0] + ass[1] + ass[2] + ass[3];
        float m = S / (float)NROWS;
        float var = SS / (float)NROWS - m * m;
        mean[c] = m;
        rstd[c] = rsqrtf(var + 1e-5f);
    }
}

__global__ void k_bnapply(const float* __restrict__ x, const float* __restrict__ mean,
                          const float* __restrict__ rstd, const float* __restrict__ g,
                          const float* __restrict__ beta, half_t* __restrict__ out) {
    int idx = blockIdx.x * 256 + threadIdx.x;
    if (idx >= NROWS * EE) return;
    int c = idx & (EE - 1);
    float v = (x[idx] - mean[c]) * rstd[c] * g[c] + beta[c];
    out[idx] = (half_t)(v > 0.f ? v : 0.f);
}

__global__ void k_packrec(const float* __restrict__ src, half_t* __restrict__ dst,
                          int Hdim, int kshift, int total) {
    int idx = blockIdx.x * 256 + threadIdx.x;
    if (idx >= total) return;
    int p = idx >> kshift;
    int k = idx & ((1 << kshift) - 1);
    int he = p >> 2, g = p & 3;
    dst[idx] = (half_t)src[((size_t)g * Hdim + he) * (size_t)(1 << kshift) + k];
}

__global__ void k_bsumenc(const float* __restrict__ bf, const float* __restrict__ bhf,
                          const float* __restrict__ bb, const float* __restrict__ bhb,
                          float* __restrict__ bsum) {
    int p = blockIdx.x * 256 + threadIdx.x;
    if (p >= 4096) return;
    int dir = p >> 11, pp = p & 2047;
    int he = pp >> 2, g = pp & 3;
    int row = g * HH + he;
    bsum[p] = dir ? (bb[row] + bhb[row]) : (bf[row] + bhf[row]);
}

__global__ __launch_bounds__(256) void k_weff(const float* __restrict__ dwhh,
                                              const float* __restrict__ dwih,
                                              const float* __restrict__ projw,
                                              half_t* __restrict__ weff,
                                              half_t* __restrict__ w0) {
    int row = blockIdx.x;
    int k = blockIdx.y * 256 + threadIdx.x;
    float v = dwhh[(size_t)row * DD + k];
    float acc = v;
    for (int m = 0; m < MM; ++m) acc += dwih[(size_t)row * MM + m] * projw[(size_t)m * DD + k];
    int p = ((row & (DD - 1)) << 2) | (row >> 10);
    weff[(size_t)p * DD + k] = (half_t)acc;
    w0[(size_t)p * DD + k] = (half_t)v;
}

__global__ void k_bdec(const float* __restrict__ dbih, const float* __restrict__ dbhh,
                       const float* __restrict__ dwih, const float* __restrict__ projb,
                       float* __restrict__ beff, float* __restrict__ b0) {
    int p = blockIdx.x * 256 + threadIdx.x;
    if (p >= 4096) return;
    int he = p >> 2, g = p & 3;
    int row = g * DD + he;
    float bb = dbih[row] + dbhh[row];
    float acc = bb;
    for (int m = 0; m < MM; ++m) acc += dwih[(size_t)row * MM + m] * projb[m];
    b0[p] = bb;
    beff[p] = acc;
}

__global__ void k_cast(const float* __restrict__ src, half_t* __restrict__ dst, int n) {
    int idx = blockIdx.x * 256 + threadIdx.x;
    if (idx < n) dst[idx] = (half_t)src[idx];
}

__global__ void k_projg(const float* __restrict__ gw, half_t* __restrict__ pg) {
    int idx = blockIdx.x * 256 + threadIdx.x;
    if (idx >= 16 * DD) return;
    int row = idx >> 10, k = idx & (DD - 1);
    pg[idx] = (half_t)(row == 0 ? gw[k] : 0.f);
}

__global__ void k_mask(const int* __restrict__ lens, float* __restrict__ out) {
    int idx = blockIdx.x * 256 + threadIdx.x;
    if (idx >= B_ * TMEL) return;
    int b = idx / TMEL, t = idx - b * TMEL;
    out[MASK_OFF + idx] = (t > lens[b]) ? 1.f : 0.f;
}

// ---------------- persistent bidirectional encoder LSTM ----------------
// 32 blocks x 1024 thr. dir=j>>4, sub=j&15 owns 32 h-elems (128 p-rows).
// 16 waves: rg=wv>>1 row-tile (8), bh=wv&1 batch half. Weights in VGPRs.
// Store: wave 0 (4 x 8B atomic swaps/lane), vmcnt ack, lanes<16 fan flags.
// Poll: wave 1 lanes<16 on private mailbox -> barrier -> contiguous load.
__global__ __launch_bounds__(1024) void k_enc(const half_t* __restrict__ X,
                                              const half_t* __restrict__ wihp,
                                              const half_t* __restrict__ whhp,
                                              const float* __restrict__ bsum,
                                              const int* __restrict__ lens,
                                              half_t* __restrict__ henc,   // ring [RING_E][2][32][512]
                                              half_t* __restrict__ hd0,    // dec ring slot 0: [32][1024]
                                              float* __restrict__ cel,     // [32][1024]
                                              unsigned* __restrict__ mbE) { // [32 consumers][64]
    const int j = blockIdx.x;
    const int dir = j >> 4, sub = j & 15;
    const int tid = threadIdx.x;
    const int wv = tid >> 6, l = tid & 63, quad = l >> 4, lo = l & 15;
    const int rg = wv >> 1, bh = wv & 1;
    const int bfr = bh * 16 + lo;
    const int ue = tid >> 5, ub = tid & 31;   // ue: h-elem within block [0,32), ub: batch

    __shared__ half_t s_hd[32 * 520];
    __shared__ float s_g[32][129];
    __shared__ float s_c[32][32];
    __shared__ float s_h[32][32];
    __shared__ half_t s_hh[32][32];
    __shared__ int s_len[32];

    if (tid < 32) s_len[tid] = lens[tid];
    s_c[ue][ub] = 0.f;
    s_h[ue][ub] = 0.f;

    const int pr = dir * 2048 + sub * 128 + rg * 16 + lo;
    const half_t* wih_b = wihp + (size_t)pr * 512;
    const half_t* whh_b = whhp + (size_t)pr * 512;
    const float bias_n = bsum[pr];

    // hoist recurrent weights into registers (constant across all 256 steps)
    h8 wihreg[16], whhreg[16];
#pragma unroll
    for (int ks = 0; ks < 16; ++ks) {
        wihreg[ks] = *(const h8*)(wih_b + ks * 32 + quad * 8);
        whhreg[ks] = *(const h8*)(whh_b + ks * 32 + quad * 8);
    }

    int sp = 0, sn = HOP;
    __syncthreads();

    for (int t = 0; t < 256; ++t) {
        // x-part MFMA first (h-independent, overlaps poll wait)
        const int lb = s_len[bfr];
        int tt = (dir == 0) ? t : (lb - 1 - t);
        tt = tt < 0 ? 0 : tt;
        const half_t* xr = X + ((size_t)bfr * 256 + tt) * 512;
        f4 accA = {0.f, 0.f, 0.f, 0.f}, accB = {0.f, 0.f, 0.f, 0.f};
#pragma unroll
        for (int ks = 0; ks < 16; ++ks) {
            h8 a = *(const h8*)(xr + ks * 32 + quad * 8);
            accA = __builtin_amdgcn_mfma_f32_16x16x32_f16(a, wihreg[ks], accA, 0, 0, 0);
        }

        // wait for all 16 same-dir producers of slot sp (slot 0 zeroed => skip)
        if (t > 0) {
            if (wv == 1 && l < 16) {
                const unsigned want = (unsigned)t;
                const unsigned* fp = mbE + (size_t)(dir * 16 + sub) * 64 + l;
                while (__hip_atomic_load(fp, __ATOMIC_RELAXED, __HIP_MEMORY_SCOPE_AGENT) < want)
                    __builtin_amdgcn_s_sleep(1);
            }
            __syncthreads();
        }

        // contiguous cooperative load of this dir's 32KB half-slot
        {
            const half_t* src = henc + (size_t)sp * 32768 + (size_t)dir * 16384;
            h8 tp[2];
#pragma unroll
            for (int i = 0; i < 2; ++i)
                tp[i] = *(const h8*)(src + (size_t)(tid + i * 1024) * 8);
#pragma unroll
            for (int i = 0; i < 2; ++i) {
                int c = tid + i * 1024;                 // h8 index [0,2048)
                *(h8*)(s_hd + (size_t)(c >> 6) * 520 + (c & 63) * 8) = tp[i];
            }
        }
        __syncthreads();

#pragma unroll
        for (int ks = 0; ks < 16; ++ks) {
            h8 a = *(const h8*)(s_hd + (size_t)bfr * 520 + ks * 32 + quad * 8);
            accB = __builtin_amdgcn_mfma_f32_16x16x32_f16(a, whhreg[ks], accB, 0, 0, 0);
        }
        const int bm = bh * 16 + quad * 4, cm = rg * 16 + lo;
#pragma unroll
        for (int r = 0; r < 4; ++r) s_g[bm + r][cm] = accA[r] + accB[r] + bias_n;
        __syncthreads();
        {
            float gi = s_g[ub][ue * 4 + 0], gf = s_g[ub][ue * 4 + 1];
            float gg = s_g[ub][ue * 4 + 2], go = s_g[ub][ue * 4 + 3];
            float cn = sigm(gf) * s_c[ue][ub] + sigm(gi) * tanh_f(gg);
            float hn = sigm(go) * tanh_f(cn);
            if (t < s_len[ub]) { s_c[ue][ub] = cn; s_h[ue][ub] = hn; }
            s_hh[ue][ub] = (half_t)s_h[ue][ub];
        }
        __syncthreads();
        if (tid < 64 && t < 255) {
            // wave 0 stores the block's 2KB chunk: 4 x 8B atomics per lane
#pragma unroll
            for (int i = 0; i < 4; ++i) {
                int s = i * 64 + tid;                   // [0,256)
                int b2 = s >> 3, e8 = (s & 7) * 4;
                union { half_t h[4]; u64 u; } pk;
#pragma unroll
                for (int q = 0; q < 4; ++q) pk.h[q] = s_hh[e8 + q][b2];
                st_atom64(henc + (size_t)sn * 32768 + (size_t)dir * 16384
                          + (size_t)b2 * 512 + sub * 32 + e8, pk.u);
            }
            // ack own data atomics, then fan out one flag per same-dir consumer
            asm volatile("s_waitcnt vmcnt(0)");
            if (tid < 16)
                st_atom32(mbE + ((size_t)(dir * 16 + tid) * 64 + sub), (unsigned)(t + 1));
        }
        if (t < 255) { sp = sn; sn += HOP; if (sn >= RING_E) sn -= RING_E; }
    }
    hd0[(size_t)ub * 1024 + dir * 512 + sub * 32 + ue] = (half_t)s_h[ue][ub];
    cel[(size_t)ub * 1024 + dir * 512 + sub * 32 + ue] = s_c[ue][ub];
}

// ---------------- persistent decoder LSTM + projection consumers ----------
// Grid 34 x 1024 thr.
//   Blocks 0..31 (core): block j owns h-elems [32j,32j+32) (p-rows
//     [128j,128j+128)). 16 waves, 1 tile/wave, Weff in VGPRs. Store: wave 0
//     4 x 8B atomics/lane, vmcnt ack, lanes<34 fan flags. Poll: wave 1
//     lanes<32 -> barrier -> contiguous cooperative 64KB load.
//   Block 32: all 128 mel rows (16 wave-tiles). Block 33: gate (2 waves).
//     Lagging consumers, never gate producers.
__global__ __launch_bounds__(1024) void k_dec(const half_t* __restrict__ Weff,
                                              const half_t* __restrict__ W0,
                                              const float* __restrict__ beff,
                                              const float* __restrict__ b0,
                                              const half_t* __restrict__ projwb,
                                              const half_t* __restrict__ projg,
                                              const float* __restrict__ projb,
                                              const float* __restrict__ gateb,
                                              const int* __restrict__ mlens,
                                              const float* __restrict__ cel,
                                              half_t* __restrict__ hd,   // ring [RING_D][32][1024]
                                              float* __restrict__ out,
                                              unsigned* __restrict__ mbD) { // [34 consumers][64]
    const int j = blockIdx.x;
    const int tid = threadIdx.x;
    const int wv = tid >> 6, l = tid & 63, quad = l >> 4, lo = l & 15;
    const int rg = wv >> 1, bh = wv & 1;
    const int bfr = bh * 16 + lo;

    __shared__ half_t s_hd[32 * 1032];
    __shared__ float s_g[32][129];
    __shared__ float s_c[32][32];
    __shared__ half_t s_hh[32][32];
    __shared__ int s_len[32];

    if (j < 32) {
        // ---------------- core recurrence block ----------------
        const int ue = tid >> 5, ub = tid & 31;

        s_c[ue][ub] = cel[(size_t)ub * 1024 + j * 32 + ue];
        const int pr = j * 128 + rg * 16 + lo;
        const float biasE = beff[pr], bias0 = b0[pr];
        const half_t* wbE = Weff + (size_t)pr * 1024;
        const half_t* wb0 = W0 + (size_t)pr * 1024;

        // hoist steady-state recurrent weights into registers
        h8 wreg[32];
#pragma unroll
        for (int ks = 0; ks < 32; ++ks)
            wreg[ks] = *(const h8*)(wbE + ks * 32 + quad * 8);

        int sp = 0, sn = HOP;
        __syncthreads();

        for (int t = 1; t <= TMEL; ++t) {
            // wait for all 32 producers of slot sp (t==1: slot 0 from k_enc)
            if (t > 1) {
                if (wv == 1 && l < 32) {
                    const unsigned want = (unsigned)(t - 1);
                    const unsigned* fp = mbD + (size_t)j * 64 + l;
                    while (__hip_atomic_load(fp, __ATOMIC_RELAXED, __HIP_MEMORY_SCOPE_AGENT) < want)
                        __builtin_amdgcn_s_sleep(1);
                }
                __syncthreads();
            }

            // contiguous cooperative load of the 64KB slot
            {
                const half_t* src = hd + (size_t)sp * 32768;
                h8 tp[4];
#pragma unroll
                for (int i = 0; i < 4; ++i)
                    tp[i] = *(const h8*)(src + (size_t)(tid + i * 1024) * 8);
#pragma unroll
                for (int i = 0; i < 4; ++i) {
                    int c = tid + i * 1024;             // h8 index [0,4096)
                    *(h8*)(s_hd + (size_t)(c >> 7) * 1032 + (c & 127) * 8) = tp[i];
                }
            }
            __syncthreads();

            const half_t* ar = s_hd + (size_t)bfr * 1032 + quad * 8;
            f4 acc = {0.f, 0.f, 0.f, 0.f}, acc2 = {0.f, 0.f, 0.f, 0.f};
            if (t == 1) {
#pragma unroll 8
                for (int ks = 0; ks < 32; ks += 2) {
                    h8 a0 = *(const h8*)(ar + ks * 32);
                    h8 a1 = *(const h8*)(ar + ks * 32 + 32);
                    acc = __builtin_amdgcn_mfma_f32_16x16x32_f16(a0, *(const h8*)(wb0 + ks * 32 + quad * 8), acc, 0, 0, 0);
                    acc2 = __builtin_amdgcn_mfma_f32_16x16x32_f16(a1, *(const h8*)(wb0 + ks * 32 + 32 + quad * 8), acc2, 0, 0, 0);
                }
            } else {
#pragma unroll
                for (int ks = 0; ks < 32; ks += 2) {
                    h8 a0 = *(const h8*)(ar + ks * 32);
                    h8 a1 = *(const h8*)(ar + ks * 32 + 32);
                    acc = __builtin_amdgcn_mfma_f32_16x16x32_f16(a0, wreg[ks], acc, 0, 0, 0);
                    acc2 = __builtin_amdgcn_mfma_f32_16x16x32_f16(a1, wreg[ks + 1], acc2, 0, 0, 0);
                }
            }
            const float bn = (t == 1) ? bias0 : biasE;
            const int bm = bh * 16 + quad * 4, cm = rg * 16 + lo;
#pragma unroll
            for (int r = 0; r < 4; ++r) s_g[bm + r][cm] = acc[r] + acc2[r] + bn;
            __syncthreads();
            {
                float gi = s_g[ub][ue * 4 + 0], gf = s_g[ub][ue * 4 + 1];
                float gg = s_g[ub][ue * 4 + 2], go = s_g[ub][ue * 4 + 3];
                float cn = sigm(gf) * s_c[ue][ub] + sigm(gi) * tanh_f(gg);
                s_c[ue][ub] = cn;
                s_hh[ue][ub] = (half_t)(sigm(go) * tanh_f(cn));
            }
            __syncthreads();
            if (tid < 64) {
                // wave 0 stores the block's 2KB chunk
#pragma unroll
                for (int i = 0; i < 4; ++i) {
                    int s = i * 64 + tid;               // [0,256)
                    int b2 = s >> 3, e8 = (s & 7) * 4;
                    union { half_t h[4]; u64 u; } pk;
#pragma unroll
                    for (int q = 0; q < 4; ++q) pk.h[q] = s_hh[e8 + q][b2];
                    st_atom64(hd + (size_t)sn * 32768 + (size_t)b2 * 1024 + j * 32 + e8, pk.u);
                }
                // ack own data atomics, then fan out one flag per consumer
                asm volatile("s_waitcnt vmcnt(0)");
                if (tid < 34)
                    st_atom32(mbD + ((size_t)tid * 64 + j), (unsigned)t);
            }
            sp = sn; sn += HOP; if (sn >= RING_D) sn -= RING_D;
        }
    } else {
        // ---------------- lagging projection consumer blocks ----------------
        const int pj = j - 32;                 // 0 = mel, 1 = gate
        const bool meld = (pj == 0);
        const bool duty = meld || (wv < 2);    // gate block: only rg==0 waves
        const half_t* pw = meld ? (projwb + (size_t)(rg * 16 + lo) * 1024)
                                : (projg + (size_t)lo * 1024);
        const float biasP = meld ? projb[rg * 16 + lo] : gateb[0];

        h8 pwreg[32];
        if (duty) {
#pragma unroll
            for (int ks = 0; ks < 32; ++ks)
                pwreg[ks] = *(const h8*)(pw + ks * 32 + quad * 8);
        }
        if (tid < 32) s_len[tid] = mlens[tid];

        int spP = HOP;
        __syncthreads();

        for (int t = 1; t <= TMEL; ++t) {
            // wait for all 32 producers of slot spP (contains h_t)
            if (wv == 1 && l < 32) {
                const unsigned want = (unsigned)t;
                const unsigned* fp = mbD + (size_t)(32 + pj) * 64 + l;
                while (__hip_atomic_load(fp, __ATOMIC_RELAXED, __HIP_MEMORY_SCOPE_AGENT) < want)
                    __builtin_amdgcn_s_sleep(1);
            }
            __syncthreads();

            // contiguous cooperative load of the 64KB slot
            {
                const half_t* src = hd + (size_t)spP * 32768;
                h8 tp[4];
#pragma unroll
                for (int i = 0; i < 4; ++i)
                    tp[i] = *(const h8*)(src + (size_t)(tid + i * 1024) * 8);
#pragma unroll
                for (int i = 0; i < 4; ++i) {
                    int c = tid + i * 1024;
                    *(h8*)(s_hd + (size_t)(c >> 7) * 1032 + (c & 127) * 8) = tp[i];
                }
            }
            __syncthreads();

            if (duty) {
                const half_t* ar = s_hd + (size_t)bfr * 1032 + quad * 8;
                f4 accm = {0.f, 0.f, 0.f, 0.f}, accm2 = {0.f, 0.f, 0.f, 0.f};
#pragma unroll
                for (int ks = 0; ks < 32; ks += 2) {
                    h8 a0 = *(const h8*)(ar + ks * 32);
                    h8 a1 = *(const h8*)(ar + ks * 32 + 32);
                    accm = __builtin_amdgcn_mfma_f32_16x16x32_f16(a0, pwreg[ks], accm, 0, 0, 0);
                    accm2 = __builtin_amdgcn_mfma_f32_16x16x32_f16(a1, pwreg[ks + 1], accm2, 0, 0, 0);
                }
                accm[0] += accm2[0]; accm[1] += accm2[1];
                accm[2] += accm2[2]; accm[3] += accm2[3];
                const int pos = t - 1;
                if (meld) {
#pragma unroll
                    for (int r = 0; r < 4; ++r) {
                        int b = bh * 16 + quad * 4 + r;
                        float v = accm[r] + biasP;
                        if (pos > s_len[b]) v = 0.f;
                        __builtin_nontemporal_store(v,
                            &out[(size_t)b * (TMEL * MM) + (size_t)pos * MM + rg * 16 + lo]);
                    }
                } else if (lo == 0) {
#pragma unroll
                    for (int r = 0; r < 4; ++r) {
                        int b = bh * 16 + quad * 4 + r;
                        float v = accm[r] + biasP;
                        if (pos > s_len[b]) v = 1000.f;
                        __builtin_nontemporal_store(v, &out[GATE_OFF + (size_t)b * TMEL + pos]);
                    }
                }
            }
            __syncthreads();   // protect s_hd before next stage
            spP += HOP; if (spP >= RING_D) spP -= RING_D;
        }
    }
}

// ---------------------------------------------------------------------------

extern "C" void kernel_launch(void* const* d_in, const int* in_sizes, int n_in,
                              void* d_out, int out_size, void* d_ws, size_t ws_size,
                              hipStream_t stream) {
    const int* x = (const int*)d_in[0];
    const int* tlens = (const int*)d_in[1];
    const int* mlens = (const int*)d_in[3];
    const float* emb = (const float*)d_in[4];
    const float* c1w = (const float*)d_in[5];
    const float* c1b = (const float*)d_in[6];
    const float* bn1g = (const float*)d_in[7];
    const float* bn1b = (const float*)d_in[8];
    const float* c2w = (const float*)d_in[9];
    const float* c2b = (const float*)d_in[10];
    const float* bn2g = (const float*)d_in[11];
    const float* bn2b = (const float*)d_in[12];
    const float* wihf = (const float*)d_in[13];
    const float* whhf = (const float*)d_in[14];
    const float* bihf = (const float*)d_in[15];
    const float* bhhf = (const float*)d_in[16];
    const float* wihb = (const float*)d_in[17];
    const float* whhb = (const float*)d_in[18];
    const float* bihb = (const float*)d_in[19];
    const float* bhhb = (const float*)d_in[20];
    const float* dwih = (const float*)d_in[21];
    const float* dwhh = (const float*)d_in[22];
    const float* dbih = (const float*)d_in[23];
    const float* dbhh = (const float*)d_in[24];
    const float* projw = (const float*)d_in[25];
    const float* projb = (const float*)d_in[26];
    const float* gatew = (const float*)d_in[27];
    const float* gateb = (const float*)d_in[28];
    float* out = (float*)d_out;
    char* ws = (char*)d_ws;

    unsigned* mbE = (unsigned*)(ws + WS_MBE);
    unsigned* mbD = (unsigned*)(ws + WS_MBD);
    half_t* henc = (half_t*)(ws + WS_HENC);
    half_t* hd = (half_t*)(ws + WS_HD);
    half_t* bufX = (half_t*)(ws + WS_BUFX);
    half_t* bufY = (half_t*)(ws + WS_BUFY);
    float* convf = (float*)(ws + WS_CONVF);
    half_t* weff = (half_t*)(ws + WS_WEFF);
    half_t* w0 = (half_t*)(ws + WS_W0);
    half_t* wp1 = (half_t*)(ws + WS_WP1);
    half_t* wp2 = (half_t*)(ws + WS_WP2);
    float* meanb = (float*)(ws + WS_MEAN);
    float* rstdb = (float*)(ws + WS_RSTD);
    half_t* wihp = (half_t*)(ws + WS_WIHP);
    half_t* whhp = (half_t*)(ws + WS_WHHP);
    float* bsum = (float*)(ws + WS_BSUM);
    float* beff = (float*)(ws + WS_BEFF);
    float* b0 = (float*)(ws + WS_B0);
    half_t* projwb = (half_t*)(ws + WS_PROJW);
    half_t* projg = (half_t*)(ws + WS_PROJG);
    float* cel = (float*)(ws + WS_CEL);

    // zero mailboxes + FULL encoder ring slot 0 (re-done every launch/replay)
    hipMemsetAsync(d_ws, 0, (size_t)WS_ZERO_BYTES, stream);

    // front-end
    k_embed<<<NROWS, 256, 0, stream>>>(x, emb, bufX);
    k_packconvw<<<(3 * EE * EE + 255) / 256, 256, 0, stream>>>(c1w, wp1);
    k_conv<<<dim3(128, 32), 256, 0, stream>>>(bufX, wp1, c1b, convf);
    k_bnstats<<<EE, 256, 0, stream>>>(convf, meanb, rstdb);
    k_bnapply<<<(NROWS * EE) / 256, 256, 0, stream>>>(convf, meanb, rstdb, bn1g, bn1b, bufY);
    k_packconvw<<<(3 * EE * EE + 255) / 256, 256, 0, stream>>>(c2w, wp2);
    k_conv<<<dim3(128, 32), 256, 0, stream>>>(bufY, wp2, c2b, convf);
    k_bnstats<<<EE, 256, 0, stream>>>(convf, meanb, rstdb);
    k_bnapply<<<(NROWS * EE) / 256, 256, 0, stream>>>(convf, meanb, rstdb, bn2g, bn2b, bufX);

    // encoder weight prep
    const int encTot = 2048 * 512;
    k_packrec<<<(encTot + 255) / 256, 256, 0, stream>>>(wihf, wihp, HH, 9, encTot);
    k_packrec<<<(encTot + 255) / 256, 256, 0, stream>>>(wihb, wihp + encTot, HH, 9, encTot);
    k_packrec<<<(encTot + 255) / 256, 256, 0, stream>>>(whhf, whhp, HH, 9, encTot);
    k_packrec<<<(encTot + 255) / 256, 256, 0, stream>>>(whhb, whhp + encTot, HH, 9, encTot);
    k_bsumenc<<<16, 256, 0, stream>>>(bihf, bhhf, bihb, bhhb, bsum);

    // persistent bidirectional encoder (writes hd ring slot 0 + cel)
    k_enc<<<32, 1024, 0, stream>>>(bufX, wihp, whhp, bsum, tlens, henc, hd, cel, mbE);

    // decoder weight prep (into retired convf region)
    k_weff<<<dim3(4096, 4), 256, 0, stream>>>(dwhh, dwih, projw, weff, w0);
    k_bdec<<<16, 256, 0, stream>>>(dbih, dbhh, dwih, projb, beff, b0);
    k_cast<<<(MM * DD + 255) / 256, 256, 0, stream>>>(projw, projwb, MM * DD);
    k_projg<<<(16 * DD + 255) / 256, 256, 0, stream>>>(gatew, projg);

    // persistent decoder (32 core + 2 projection blocks)
    k_dec<<<34, 1024, 0, stream>>>(weff, w0, beff, b0, projwb, projg, projb, gateb,
                                   mlens, cel, hd, out, mbD);

    // mask output
    k_mask<<<(B_ * TMEL + 255) / 256, 256, 0, stream>>>(mlens, out);

    (void)in_sizes; (void)n_in; (void)out_size; (void)ws_size;
}

// Round 7
// 5149.203 us; speedup vs baseline: 2.2428x; 2.2428x over previous
//
#include <hip/hip_runtime.h>

// ---------------------------------------------------------------------------
// TTS forward on MI355X.
//   embed -> conv1(+BN+ReLU) -> conv2(+BN+ReLU) -> persistent biLSTM encoder
//   -> W_eff fold (decoder input GEMM folded into recurrent weights)
//   -> persistent 800-step decoder LSTM + lagging projection consumer blocks
// Round 10: revert to the round-7 structure (best measured: 64x512 blocks,
// single store wave w/ atomic-swap data + vmcnt ack + flag fan-out, poll-one-
// wave -> barrier -> contiguous coop load), with ONE change: small REUSED
// L3-resident rings (RING_D=101, RING_E=33) so producer atomics hit warm L3
// lines (no cold-line HBM write-allocate on the ack path). Consumer data
// loads become sc0/sc1 (L1/L2-bypassing) so reuse cannot serve stale L2
// lines. Full 64KB encoder slot 0 zeroed.
// ---------------------------------------------------------------------------

typedef float f4 __attribute__((ext_vector_type(4)));
typedef _Float16 h8 __attribute__((ext_vector_type(8)));
typedef _Float16 half_t;
typedef unsigned u4 __attribute__((ext_vector_type(4)));
typedef unsigned long long u64;

#define B_    32
#define LTXT  256
#define TMEL  800
#define EE    512
#define HH    512
#define DD    1024
#define MM    128
#define NROWS 8192          // B_*LTXT
#define GATE_OFF 3276800    // B_*TMEL*MM
#define MASK_OFF 3302400    // + B_*TMEL

#define RING_D 101          // decoder h ring slots (reused; L3-resident 6.6MB)
#define RING_E 33           // encoder h ring slots (2.1MB)
#define HOP    13           // slot hop stride (coprime with both ring sizes)

// workspace offsets (bytes)
#define WS_MBE        0ull             // enc mailboxes: 64 consumers x 64 u32 = 16 KiB
#define WS_MBD        16384ull         // dec mailboxes: 73 consumers x 64 u32 (32 KiB rsvd)
#define WS_HENC       49152ull         // RING_E * 65536 = 2,162,688
#define WS_ZERO_BYTES 114688ull        // mailboxes + FULL henc slot 0 (64KB)
#define WS_HD         2211840ull       // RING_D * 65536 = 6,619,136
#define WS_BUFX       8830976ull       // 8 MiB
#define WS_BUFY       17219584ull      // 8 MiB
#define WS_CONVF      25608192ull      // 16 MiB (reused by WEFF/W0 after convs)
#define WS_WEFF       25608192ull
#define WS_W0         33996800ull
#define WS_WP1        42385408ull
#define WS_WP2        43958272ull
#define WS_WIHP       45531136ull      // 4 MiB
#define WS_WHHP       49725440ull      // 4 MiB
#define WS_BSUM       53919744ull
#define WS_BEFF       53936128ull
#define WS_B0         53952512ull
#define WS_MEAN       53968896ull
#define WS_RSTD       53970944ull
#define WS_PROJW      53972992ull
#define WS_PROJG      54235136ull
#define WS_CEL        54267904ull
// total ~54.4 MB

__device__ __forceinline__ float sigm(float x) { return 1.f / (1.f + __expf(-x)); }
__device__ __forceinline__ float tanh_f(float x) {
    float e = __expf(2.f * x);
    return 1.f - 2.f / (e + 1.f);
}

// return-less atomic swap: executes at coherence point, line stays L3-resident
__device__ __forceinline__ void st_atom64(void* p, u64 v) {
    asm volatile("global_atomic_swap_x2 %0, %1, off" :: "v"(p), "v"(v) : "memory");
}
__device__ __forceinline__ void st_atom32(unsigned* p, unsigned v) {
    asm volatile("global_atomic_swap %0, %1, off" :: "v"(p), "v"(v) : "memory");
}
// coherent 16B load: bypass L1/L2, served at the coherence point (L3)
__device__ __forceinline__ u4 ld_l3(const void* p) {
    u4 r;
    asm volatile("global_load_dwordx4 %0, %1, off sc0 sc1" : "=v"(r) : "v"(p) : "memory");
    return r;
}
__device__ __forceinline__ void wait_vm0() {
    asm volatile("s_waitcnt vmcnt(0)" ::: "memory");
    __builtin_amdgcn_sched_barrier(0);
}

// ---------------- small prep kernels ----------------

__global__ void k_embed(const int* __restrict__ x, const float* __restrict__ emb,
                        half_t* __restrict__ out) {
    int row = blockIdx.x;
    int tok = x[row];
    const float* e = emb + (size_t)tok * EE;
    half_t* o = out + (size_t)row * EE;
    for (int c = threadIdx.x; c < EE; c += blockDim.x) o[c] = (half_t)e[c];
}

__global__ void k_packconvw(const float* __restrict__ w, half_t* __restrict__ wp) {
    int idx = blockIdx.x * 256 + threadIdx.x;
    if (idx >= 3 * EE * EE) return;
    int s = idx / (EE * EE);
    int rem = idx - s * EE * EE;
    int eo = rem >> 9, ei = rem & 511;
    wp[idx] = (half_t)w[(size_t)eo * (EE * 3) + ei * 3 + s];
}

__global__ __launch_bounds__(256) void k_conv(const half_t* __restrict__ A,
                                              const half_t* __restrict__ Wp,
                                              const float* __restrict__ bias,
                                              float* __restrict__ out) {
    const int nt = blockIdx.x, et = blockIdx.y;
    const int tid = threadIdx.x;
    const int wv = tid >> 6, l = tid & 63, quad = l >> 4, lo = l & 15;
    const int rowA = nt * 64 + wv * 16 + lo;
    const int eo = et * 16 + lo;
    f4 acc = {0.f, 0.f, 0.f, 0.f};
    for (int s = 0; s < 3; ++s) {
        int lsp = (rowA & 255) + s - 1;
        bool valid = (lsp >= 0) && (lsp < 256);
        int rs = rowA + s - 1;
        rs = rs < 0 ? 0 : (rs > NROWS - 1 ? NROWS - 1 : rs);
        const half_t* ab = A + (size_t)rs * EE;
        const half_t* wb = Wp + ((size_t)s * EE + eo) * EE;
#pragma unroll 4
        for (int ks = 0; ks < 16; ++ks) {
            h8 a = {0, 0, 0, 0, 0, 0, 0, 0};
            if (valid) a = *(const h8*)(ab + ks * 32 + quad * 8);
            h8 b = *(const h8*)(wb + ks * 32 + quad * 8);
            acc = __builtin_amdgcn_mfma_f32_16x16x32_f16(a, b, acc, 0, 0, 0);
        }
    }
    const int orow = nt * 64 + wv * 16 + quad * 4;
    const float bv = bias[eo];
#pragma unroll
    for (int r = 0; r < 4; ++r) out[(size_t)(orow + r) * EE + eo] = acc[r] + bv;
}

__global__ __launch_bounds__(256) void k_bnstats(const float* __restrict__ x,
                                                 float* __restrict__ mean,
                                                 float* __restrict__ rstd) {
    const int c = blockIdx.x;
    float s = 0.f, ss = 0.f;
    for (int n = threadIdx.x; n < NROWS; n += 256) {
        float v = x[(size_t)n * EE + c];
        s += v; ss += v * v;
    }
#pragma unroll
    for (int off = 32; off > 0; off >>= 1) { s += __shfl_down(s, off); ss += __shfl_down(ss, off); }
    __shared__ float as[4], ass[4];
    int wv = threadIdx.x >> 6;
    if ((threadIdx.x & 63) == 0) { as[wv] = s; ass[wv] = ss; }
    __syncthreads();
    if (threadIdx.x == 0) {
        float S = as[0] + as[1] + as[2] + as[3];
        float SS = ass[0] + ass[1] + ass[2] + ass[3];
        float m = S / (float)NROWS;
        float var = SS / (float)NROWS - m * m;
        mean[c] = m;
        rstd[c] = rsqrtf(var + 1e-5f);
    }
}

__global__ void k_bnapply(const float* __restrict__ x, const float* __restrict__ mean,
                          const float* __restrict__ rstd, const float* __restrict__ g,
                          const float* __restrict__ beta, half_t* __restrict__ out) {
    int idx = blockIdx.x * 256 + threadIdx.x;
    if (idx >= NROWS * EE) return;
    int c = idx & (EE - 1);
    float v = (x[idx] - mean[c]) * rstd[c] * g[c] + beta[c];
    out[idx] = (half_t)(v > 0.f ? v : 0.f);
}

__global__ void k_packrec(const float* __restrict__ src, half_t* __restrict__ dst,
                          int Hdim, int kshift, int total) {
    int idx = blockIdx.x * 256 + threadIdx.x;
    if (idx >= total) return;
    int p = idx >> kshift;
    int k = idx & ((1 << kshift) - 1);
    int he = p >> 2, g = p & 3;
    dst[idx] = (half_t)src[((size_t)g * Hdim + he) * (size_t)(1 << kshift) + k];
}

__global__ void k_bsumenc(const float* __restrict__ bf, const float* __restrict__ bhf,
                          const float* __restrict__ bb, const float* __restrict__ bhb,
                          float* __restrict__ bsum) {
    int p = blockIdx.x * 256 + threadIdx.x;
    if (p >= 4096) return;
    int dir = p >> 11, pp = p & 2047;
    int he = pp >> 2, g = pp & 3;
    int row = g * HH + he;
    bsum[p] = dir ? (bb[row] + bhb[row]) : (bf[row] + bhf[row]);
}

__global__ __launch_bounds__(256) void k_weff(const float* __restrict__ dwhh,
                                              const float* __restrict__ dwih,
                                              const float* __restrict__ projw,
                                              half_t* __restrict__ weff,
                                              half_t* __restrict__ w0) {
    int row = blockIdx.x;
    int k = blockIdx.y * 256 + threadIdx.x;
    float v = dwhh[(size_t)row * DD + k];
    float acc = v;
    for (int m = 0; m < MM; ++m) acc += dwih[(size_t)row * MM + m] * projw[(size_t)m * DD + k];
    int p = ((row & (DD - 1)) << 2) | (row >> 10);
    weff[(size_t)p * DD + k] = (half_t)acc;
    w0[(size_t)p * DD + k] = (half_t)v;
}

__global__ void k_bdec(const float* __restrict__ dbih, const float* __restrict__ dbhh,
                       const float* __restrict__ dwih, const float* __restrict__ projb,
                       float* __restrict__ beff, float* __restrict__ b0) {
    int p = blockIdx.x * 256 + threadIdx.x;
    if (p >= 4096) return;
    int he = p >> 2, g = p & 3;
    int row = g * DD + he;
    float bb = dbih[row] + dbhh[row];
    float acc = bb;
    for (int m = 0; m < MM; ++m) acc += dwih[(size_t)row * MM + m] * projb[m];
    b0[p] = bb;
    beff[p] = acc;
}

__global__ void k_cast(const float* __restrict__ src, half_t* __restrict__ dst, int n) {
    int idx = blockIdx.x * 256 + threadIdx.x;
    if (idx < n) dst[idx] = (half_t)src[idx];
}

__global__ void k_projg(const float* __restrict__ gw, half_t* __restrict__ pg) {
    int idx = blockIdx.x * 256 + threadIdx.x;
    if (idx >= 16 * DD) return;
    int row = idx >> 10, k = idx & (DD - 1);
    pg[idx] = (half_t)(row == 0 ? gw[k] : 0.f);
}

__global__ void k_mask(const int* __restrict__ lens, float* __restrict__ out) {
    int idx = blockIdx.x * 256 + threadIdx.x;
    if (idx >= B_ * TMEL) return;
    int b = idx / TMEL, t = idx - b * TMEL;
    out[MASK_OFF + idx] = (t > lens[b]) ? 1.f : 0.f;
}

// ---------------- persistent bidirectional encoder LSTM ----------------
// 64 blocks x 512 thr. dir=j>>5, sub=j&31 owns 16 h-elems. Recurrent weights
// in VGPRs. Store: wave 0, two 8B atomic swaps/lane (warm L3 lines), vmcnt
// ack, lanes<32 fan one flag atomic per same-dir consumer. Poll: wave 1
// lanes<32. Data loads: sc0/sc1 coherent (ring reused; no stale L2).
__global__ __launch_bounds__(512) void k_enc(const half_t* __restrict__ X,
                                             const half_t* __restrict__ wihp,
                                             const half_t* __restrict__ whhp,
                                             const float* __restrict__ bsum,
                                             const int* __restrict__ lens,
                                             half_t* __restrict__ henc,   // ring [RING_E][2][32][512]
                                             half_t* __restrict__ hd0,    // dec ring slot 0: [32][1024]
                                             float* __restrict__ cel,     // [32][1024]
                                             unsigned* __restrict__ mbE) { // [64 consumers][64]
    const int j = blockIdx.x;
    const int dir = j >> 5, sub = j & 31;
    const int tid = threadIdx.x;
    const int wv = tid >> 6, l = tid & 63, quad = l >> 4, lo = l & 15;
    const int rg = wv >> 1, bh = wv & 1;
    const int bfr = bh * 16 + lo;
    const int ue = tid >> 5, ub = tid & 31;

    __shared__ half_t s_hd[32 * 520];
    __shared__ float s_g[32][65];
    __shared__ float s_c[16][32];
    __shared__ float s_h[16][32];
    __shared__ half_t s_hh[16][32];
    __shared__ int s_len[32];

    if (tid < 32) s_len[tid] = lens[tid];
    s_c[ue][ub] = 0.f;
    s_h[ue][ub] = 0.f;

    const int pr = dir * 2048 + sub * 64 + rg * 16 + lo;
    const half_t* wih_b = wihp + (size_t)pr * 512;
    const half_t* whh_b = whhp + (size_t)pr * 512;
    const float bias_n = bsum[pr];

    // hoist recurrent weights into registers (constant across all 256 steps)
    h8 wihreg[16], whhreg[16];
#pragma unroll
    for (int ks = 0; ks < 16; ++ks) {
        wihreg[ks] = *(const h8*)(wih_b + ks * 32 + quad * 8);
        whhreg[ks] = *(const h8*)(whh_b + ks * 32 + quad * 8);
    }

    int sp = 0, sn = HOP;
    __syncthreads();

    for (int t = 0; t < 256; ++t) {
        // wait for all producers of slot sp (slot 0 pre-zeroed => skip)
        if (t > 0) {
            if (tid >= 64 && tid < 96) {
                const unsigned want = (unsigned)t;
                const unsigned* fp = mbE + (size_t)(dir * 32 + sub) * 64 + (tid - 64);
                while (__hip_atomic_load(fp, __ATOMIC_RELAXED, __HIP_MEMORY_SCOPE_AGENT) < want)
                    __builtin_amdgcn_s_sleep(1);
            }
            __syncthreads();
        }

        // issue coherent h-slot loads (bypass L1/L2; L3 has fresh data)
        const half_t* src = henc + (size_t)sp * 32768 + (size_t)dir * 16384;
        u4 tmp0 = ld_l3(src + (size_t)(tid + 0 * 512) * 8);
        u4 tmp1 = ld_l3(src + (size_t)(tid + 1 * 512) * 8);
        u4 tmp2 = ld_l3(src + (size_t)(tid + 2 * 512) * 8);
        u4 tmp3 = ld_l3(src + (size_t)(tid + 3 * 512) * 8);

        // x-part MFMA overlaps the h loads (a from global X, b from regs)
        const int lb = s_len[bfr];
        int tt = (dir == 0) ? t : (lb - 1 - t);
        tt = tt < 0 ? 0 : tt;
        const half_t* xr = X + ((size_t)bfr * 256 + tt) * 512;
        f4 accA = {0.f, 0.f, 0.f, 0.f}, accB = {0.f, 0.f, 0.f, 0.f};
#pragma unroll
        for (int ks = 0; ks < 16; ++ks) {
            h8 a = *(const h8*)(xr + ks * 32 + quad * 8);
            accA = __builtin_amdgcn_mfma_f32_16x16x32_f16(a, wihreg[ks], accA, 0, 0, 0);
        }

        // stage h into LDS (wait for the asm loads first)
        wait_vm0();
        {
            int c0 = tid;
            *(u4*)(s_hd + (size_t)(c0 >> 6) * 520 + (c0 & 63) * 8) = tmp0;
            int c1 = tid + 512;
            *(u4*)(s_hd + (size_t)(c1 >> 6) * 520 + (c1 & 63) * 8) = tmp1;
            int c2 = tid + 1024;
            *(u4*)(s_hd + (size_t)(c2 >> 6) * 520 + (c2 & 63) * 8) = tmp2;
            int c3 = tid + 1536;
            *(u4*)(s_hd + (size_t)(c3 >> 6) * 520 + (c3 & 63) * 8) = tmp3;
        }
        __syncthreads();

#pragma unroll
        for (int ks = 0; ks < 16; ++ks) {
            h8 a = *(const h8*)(s_hd + (size_t)bfr * 520 + ks * 32 + quad * 8);
            accB = __builtin_amdgcn_mfma_f32_16x16x32_f16(a, whhreg[ks], accB, 0, 0, 0);
        }
        const int bm = bh * 16 + quad * 4, cm = rg * 16 + lo;
#pragma unroll
        for (int r = 0; r < 4; ++r) s_g[bm + r][cm] = accA[r] + accB[r] + bias_n;
        __syncthreads();
        {
            float gi = s_g[ub][ue * 4 + 0], gf = s_g[ub][ue * 4 + 1];
            float gg = s_g[ub][ue * 4 + 2], go = s_g[ub][ue * 4 + 3];
            float cn = sigm(gf) * s_c[ue][ub] + sigm(gi) * tanh_f(gg);
            float hn = sigm(go) * tanh_f(cn);
            if (t < s_len[ub]) { s_c[ue][ub] = cn; s_h[ue][ub] = hn; }
            s_hh[ue][ub] = (half_t)s_h[ue][ub];
        }
        __syncthreads();
        if (tid < 64 && t < 255) {
            int b2 = tid >> 1, e8 = (tid & 1) * 8;
            union { half_t h[8]; u64 u[2]; } pk;
#pragma unroll
            for (int i = 0; i < 8; ++i) pk.h[i] = s_hh[e8 + i][b2];
            half_t* dst = henc + (size_t)sn * 32768 + (size_t)dir * 16384
                          + (size_t)b2 * 512 + sub * 16 + e8;
            st_atom64(dst, pk.u[0]);
            st_atom64(dst + 4, pk.u[1]);
            // ack own data atomics (true global visibility), then fan out flags
            asm volatile("s_waitcnt vmcnt(0)");
            if (tid < 32)
                st_atom32(mbE + ((size_t)(dir * 32 + tid) * 64 + sub), (unsigned)(t + 1));
        }
        if (t < 255) { sp = sn; sn += HOP; if (sn >= RING_E) sn -= RING_E; }
    }
    hd0[(size_t)ub * 1024 + dir * 512 + sub * 16 + ue] = (half_t)s_h[ue][ub];
    cel[(size_t)ub * 1024 + dir * 512 + sub * 16 + ue] = s_c[ue][ub];
}

// ---------------- persistent decoder LSTM + projection consumers ----------
// Grid 73 x 512 thr.
//   Blocks 0..63 (core): block j owns h-elems [16j,16j+16). Weff fragments
//     in VGPRs; h ring slots hop by HOP mod RING_D; slot 0 = encoder hid.
//     Store: wave 0, two 8B atomic swaps/lane (warm L3); 1 flag/producer
//     fanned to 73 consumers. Poll: wave 1. Loads: sc0/sc1 coherent.
//   Blocks 64..72 (proj): lagging consumers; block 64+p computes mel rows
//     [16p,16p+16) (p<8) or gate (p==8) for pos t-1 from h_t.
__global__ __launch_bounds__(512) void k_dec(const half_t* __restrict__ Weff,
                                             const half_t* __restrict__ W0,
                                             const float* __restrict__ beff,
                                             const float* __restrict__ b0,
                                             const half_t* __restrict__ projwb,
                                             const half_t* __restrict__ projg,
                                             const float* __restrict__ projb,
                                             const float* __restrict__ gateb,
                                             const int* __restrict__ mlens,
                                             const float* __restrict__ cel,
                                             half_t* __restrict__ hd,   // ring [RING_D][32][1024]
                                             float* __restrict__ out,
                                             unsigned* __restrict__ mbD) { // [73 consumers][64]
    const int j = blockIdx.x;
    const int tid = threadIdx.x;
    const int wv = tid >> 6, l = tid & 63, quad = l >> 4, lo = l & 15;

    __shared__ half_t s_hd[32 * 1032];
    __shared__ float s_g[32][65];
    __shared__ float s_c[16][32];
    __shared__ half_t s_hh[16][32];
    __shared__ int s_len[32];

    if (j < 64) {
        // ---------------- core recurrence block ----------------
        const int rg = wv >> 1, bh = wv & 1;
        const int bfr = bh * 16 + lo;
        const int ue = tid >> 5, ub = tid & 31;

        s_c[ue][ub] = cel[(size_t)ub * 1024 + j * 16 + ue];
        const int pr = j * 64 + rg * 16 + lo;
        const float biasE = beff[pr], bias0 = b0[pr];
        const half_t* wbE = Weff + (size_t)pr * 1024;
        const half_t* wb0 = W0 + (size_t)pr * 1024;

        // hoist steady-state recurrent weights into registers
        h8 wreg[32];
#pragma unroll
        for (int ks = 0; ks < 32; ++ks)
            wreg[ks] = *(const h8*)(wbE + ks * 32 + quad * 8);

        int sp = 0, sn = HOP;
        __syncthreads();

        for (int t = 1; t <= TMEL; ++t) {
            // wait for all producers of slot sp (t==1: slot 0 from k_enc,
            // visible via kernel-boundary coherence => skip)
            if (t > 1) {
                if (tid >= 64 && tid < 128) {
                    const unsigned want = (unsigned)(t - 1);
                    const unsigned* fp = mbD + (size_t)j * 64 + (tid - 64);
                    while (__hip_atomic_load(fp, __ATOMIC_RELAXED, __HIP_MEMORY_SCOPE_AGENT) < want)
                        __builtin_amdgcn_s_sleep(1);
                }
                __syncthreads();
            }

            // coherent cooperative load of h slot (bypass L1/L2)
            {
                const half_t* src = hd + (size_t)sp * 32768;
                u4 tp[8];
#pragma unroll
                for (int i = 0; i < 8; ++i)
                    tp[i] = ld_l3(src + (size_t)(tid + i * 512) * 8);
                wait_vm0();
#pragma unroll
                for (int i = 0; i < 8; ++i) {
                    int c = tid + i * 512;
                    *(u4*)(s_hd + (size_t)(c >> 7) * 1032 + (c & 127) * 8) = tp[i];
                }
            }
            __syncthreads();

            const half_t* ar = s_hd + (size_t)bfr * 1032 + quad * 8;
            f4 acc = {0.f, 0.f, 0.f, 0.f}, acc2 = {0.f, 0.f, 0.f, 0.f};
            if (t == 1) {
#pragma unroll 8
                for (int ks = 0; ks < 32; ks += 2) {
                    h8 a0 = *(const h8*)(ar + ks * 32);
                    h8 a1 = *(const h8*)(ar + ks * 32 + 32);
                    acc = __builtin_amdgcn_mfma_f32_16x16x32_f16(a0, *(const h8*)(wb0 + ks * 32 + quad * 8), acc, 0, 0, 0);
                    acc2 = __builtin_amdgcn_mfma_f32_16x16x32_f16(a1, *(const h8*)(wb0 + ks * 32 + 32 + quad * 8), acc2, 0, 0, 0);
                }
            } else {
#pragma unroll
                for (int ks = 0; ks < 32; ks += 2) {
                    h8 a0 = *(const h8*)(ar + ks * 32);
                    h8 a1 = *(const h8*)(ar + ks * 32 + 32);
                    acc = __builtin_amdgcn_mfma_f32_16x16x32_f16(a0, wreg[ks], acc, 0, 0, 0);
                    acc2 = __builtin_amdgcn_mfma_f32_16x16x32_f16(a1, wreg[ks + 1], acc2, 0, 0, 0);
                }
            }
            const float bn = (t == 1) ? bias0 : biasE;
            const int bm = bh * 16 + quad * 4, cm = rg * 16 + lo;
#pragma unroll
            for (int r = 0; r < 4; ++r) s_g[bm + r][cm] = acc[r] + acc2[r] + bn;
            __syncthreads();
            {
                float gi = s_g[ub][ue * 4 + 0], gf = s_g[ub][ue * 4 + 1];
                float gg = s_g[ub][ue * 4 + 2], go = s_g[ub][ue * 4 + 3];
                float cn = sigm(gf) * s_c[ue][ub] + sigm(gi) * tanh_f(gg);
                s_c[ue][ub] = cn;
                s_hh[ue][ub] = (half_t)(sigm(go) * tanh_f(cn));
            }
            __syncthreads();
            if (tid < 64) {
                int b2 = tid >> 1, e8 = (tid & 1) * 8;
                union { half_t h[8]; u64 u[2]; } pk;
#pragma unroll
                for (int i = 0; i < 8; ++i) pk.h[i] = s_hh[e8 + i][b2];
                half_t* dst = hd + (size_t)sn * 32768 + (size_t)b2 * 1024 + j * 16 + e8;
                st_atom64(dst, pk.u[0]);
                st_atom64(dst + 4, pk.u[1]);
                // ack own data atomics, then fan out one flag per consumer
                asm volatile("s_waitcnt vmcnt(0)");
                st_atom32(mbD + ((size_t)tid * 64 + j), (unsigned)t);
                if (tid < 9)
                    st_atom32(mbD + ((size_t)(64 + tid) * 64 + j), (unsigned)t);
            }
            sp = sn; sn += HOP; if (sn >= RING_D) sn -= RING_D;
        }
    } else {
        // ---------------- lagging projection consumer block ----------------
        const int pj = j - 64;
        const bool meld = (pj < 8);
        const bool duty = (wv < 2);
        const int bh2 = wv & 1;
        const half_t* pw = meld ? (projwb + (size_t)(pj * 16 + lo) * 1024)
                                : (projg + (size_t)lo * 1024);
        const float biasP = meld ? projb[pj * 16 + lo] : gateb[0];

        h8 pwreg[32];
        if (duty) {
#pragma unroll
            for (int ks = 0; ks < 32; ++ks)
                pwreg[ks] = *(const h8*)(pw + ks * 32 + quad * 8);
        }
        if (tid < 32) s_len[tid] = mlens[tid];

        int spP = HOP;
        __syncthreads();

        for (int t = 1; t <= TMEL; ++t) {
            // wait for all producers of slot spP (contains h_t)
            if (tid < 64) {
                const unsigned want = (unsigned)t;
                const unsigned* fp = mbD + (size_t)(64 + pj) * 64 + tid;
                while (__hip_atomic_load(fp, __ATOMIC_RELAXED, __HIP_MEMORY_SCOPE_AGENT) < want)
                    __builtin_amdgcn_s_sleep(1);
            }
            __syncthreads();

            // coherent cooperative load of h_t slot
            {
                const half_t* src = hd + (size_t)spP * 32768;
                u4 tp[8];
#pragma unroll
                for (int i = 0; i < 8; ++i)
                    tp[i] = ld_l3(src + (size_t)(tid + i * 512) * 8);
                wait_vm0();
#pragma unroll
                for (int i = 0; i < 8; ++i) {
                    int c = tid + i * 512;
                    *(u4*)(s_hd + (size_t)(c >> 7) * 1032 + (c & 127) * 8) = tp[i];
                }
            }
            __syncthreads();

            if (duty) {
                const half_t* ar = s_hd + (size_t)(bh2 * 16 + lo) * 1032 + quad * 8;
                f4 accm = {0.f, 0.f, 0.f, 0.f}, accm2 = {0.f, 0.f, 0.f, 0.f};
#pragma unroll
                for (int ks = 0; ks < 32; ks += 2) {
                    h8 a0 = *(const h8*)(ar + ks * 32);
                    h8 a1 = *(const h8*)(ar + ks * 32 + 32);
                    accm = __builtin_amdgcn_mfma_f32_16x16x32_f16(a0, pwreg[ks], accm, 0, 0, 0);
                    accm2 = __builtin_amdgcn_mfma_f32_16x16x32_f16(a1, pwreg[ks + 1], accm2, 0, 0, 0);
                }
                accm[0] += accm2[0]; accm[1] += accm2[1];
                accm[2] += accm2[2]; accm[3] += accm2[3];
                const int pos = t - 1;
                if (meld) {
#pragma unroll
                    for (int r = 0; r < 4; ++r) {
                        int b = bh2 * 16 + quad * 4 + r;
                        float v = accm[r] + biasP;
                        if (pos > s_len[b]) v = 0.f;
                        __builtin_nontemporal_store(v,
                            &out[(size_t)b * (TMEL * MM) + (size_t)pos * MM + pj * 16 + lo]);
                    }
                } else if (lo == 0) {
#pragma unroll
                    for (int r = 0; r < 4; ++r) {
                        int b = bh2 * 16 + quad * 4 + r;
                        float v = accm[r] + biasP;
                        if (pos > s_len[b]) v = 1000.f;
                        __builtin_nontemporal_store(v, &out[GATE_OFF + (size_t)b * TMEL + pos]);
                    }
                }
            }
            __syncthreads();   // protect s_hd before next stage
            spP += HOP; if (spP >= RING_D) spP -= RING_D;
        }
    }
}

// ---------------------------------------------------------------------------

extern "C" void kernel_launch(void* const* d_in, const int* in_sizes, int n_in,
                              void* d_out, int out_size, void* d_ws, size_t ws_size,
                              hipStream_t stream) {
    const int* x = (const int*)d_in[0];
    const int* tlens = (const int*)d_in[1];
    const int* mlens = (const int*)d_in[3];
    const float* emb = (const float*)d_in[4];
    const float* c1w = (const float*)d_in[5];
    const float* c1b = (const float*)d_in[6];
    const float* bn1g = (const float*)d_in[7];
    const float* bn1b = (const float*)d_in[8];
    const float* c2w = (const float*)d_in[9];
    const float* c2b = (const float*)d_in[10];
    const float* bn2g = (const float*)d_in[11];
    const float* bn2b = (const float*)d_in[12];
    const float* wihf = (const float*)d_in[13];
    const float* whhf = (const float*)d_in[14];
    const float* bihf = (const float*)d_in[15];
    const float* bhhf = (const float*)d_in[16];
    const float* wihb = (const float*)d_in[17];
    const float* whhb = (const float*)d_in[18];
    const float* bihb = (const float*)d_in[19];
    const float* bhhb = (const float*)d_in[20];
    const float* dwih = (const float*)d_in[21];
    const float* dwhh = (const float*)d_in[22];
    const float* dbih = (const float*)d_in[23];
    const float* dbhh = (const float*)d_in[24];
    const float* projw = (const float*)d_in[25];
    const float* projb = (const float*)d_in[26];
    const float* gatew = (const float*)d_in[27];
    const float* gateb = (const float*)d_in[28];
    float* out = (float*)d_out;
    char* ws = (char*)d_ws;

    unsigned* mbE = (unsigned*)(ws + WS_MBE);
    unsigned* mbD = (unsigned*)(ws + WS_MBD);
    half_t* henc = (half_t*)(ws + WS_HENC);
    half_t* hd = (half_t*)(ws + WS_HD);
    half_t* bufX = (half_t*)(ws + WS_BUFX);
    half_t* bufY = (half_t*)(ws + WS_BUFY);
    float* convf = (float*)(ws + WS_CONVF);
    half_t* weff = (half_t*)(ws + WS_WEFF);
    half_t* w0 = (half_t*)(ws + WS_W0);
    half_t* wp1 = (half_t*)(ws + WS_WP1);
    half_t* wp2 = (half_t*)(ws + WS_WP2);
    float* meanb = (float*)(ws + WS_MEAN);
    float* rstdb = (float*)(ws + WS_RSTD);
    half_t* wihp = (half_t*)(ws + WS_WIHP);
    half_t* whhp = (half_t*)(ws + WS_WHHP);
    float* bsum = (float*)(ws + WS_BSUM);
    float* beff = (float*)(ws + WS_BEFF);
    float* b0 = (float*)(ws + WS_B0);
    half_t* projwb = (half_t*)(ws + WS_PROJW);
    half_t* projg = (half_t*)(ws + WS_PROJG);
    float* cel = (float*)(ws + WS_CEL);

    // zero mailboxes + FULL encoder ring slot 0 (re-done every launch/replay)
    hipMemsetAsync(d_ws, 0, (size_t)WS_ZERO_BYTES, stream);

    // front-end
    k_embed<<<NROWS, 256, 0, stream>>>(x, emb, bufX);
    k_packconvw<<<(3 * EE * EE + 255) / 256, 256, 0, stream>>>(c1w, wp1);
    k_conv<<<dim3(128, 32), 256, 0, stream>>>(bufX, wp1, c1b, convf);
    k_bnstats<<<EE, 256, 0, stream>>>(convf, meanb, rstdb);
    k_bnapply<<<(NROWS * EE) / 256, 256, 0, stream>>>(convf, meanb, rstdb, bn1g, bn1b, bufY);
    k_packconvw<<<(3 * EE * EE + 255) / 256, 256, 0, stream>>>(c2w, wp2);
    k_conv<<<dim3(128, 32), 256, 0, stream>>>(bufY, wp2, c2b, convf);
    k_bnstats<<<EE, 256, 0, stream>>>(convf, meanb, rstdb);
    k_bnapply<<<(NROWS * EE) / 256, 256, 0, stream>>>(convf, meanb, rstdb, bn2g, bn2b, bufX);

    // encoder weight prep
    const int encTot = 2048 * 512;
    k_packrec<<<(encTot + 255) / 256, 256, 0, stream>>>(wihf, wihp, HH, 9, encTot);
    k_packrec<<<(encTot + 255) / 256, 256, 0, stream>>>(wihb, wihp + encTot, HH, 9, encTot);
    k_packrec<<<(encTot + 255) / 256, 256, 0, stream>>>(whhf, whhp, HH, 9, encTot);
    k_packrec<<<(encTot + 255) / 256, 256, 0, stream>>>(whhb, whhp + encTot, HH, 9, encTot);
    k_bsumenc<<<16, 256, 0, stream>>>(bihf, bhhf, bihb, bhhb, bsum);

    // persistent bidirectional encoder (writes hd ring slot 0 + cel)
    k_enc<<<64, 512, 0, stream>>>(bufX, wihp, whhp, bsum, tlens, henc, hd, cel, mbE);

    // decoder weight prep (into retired convf region)
    k_weff<<<dim3(4096, 4), 256, 0, stream>>>(dwhh, dwih, projw, weff, w0);
    k_bdec<<<16, 256, 0, stream>>>(dbih, dbhh, dwih, projb, beff, b0);
    k_cast<<<(MM * DD + 255) / 256, 256, 0, stream>>>(projw, projwb, MM * DD);
    k_projg<<<(16 * DD + 255) / 256, 256, 0, stream>>>(gatew, projg);

    // persistent decoder (64 core + 9 projection blocks)
    k_dec<<<73, 512, 0, stream>>>(weff, w0, beff, b0, projwb, projg, projb, gateb,
                                  mlens, cel, hd, out, mbD);

    // mask output
    k_mask<<<(B_ * TMEL + 255) / 256, 256, 0, stream>>>(mlens, out);

    (void)in_sizes; (void)n_in; (void)out_size; (void)ws_size;
}